// Round 8
// baseline (235.698 us; speedup 1.0000x reference)
//
#include <hip/hip_runtime.h>
#include <math.h>

#define N_TOT 8400
#define MASK_WORDS 132   // ceil(8400/64)
#define CAP 32           // max (word,bits) entries per row
#define RT 33            // rank tiles: ceil(8400/256)
#define GRID 256         // blocks (1 per CU, all co-resident)
#define BTHR 256

typedef unsigned long long u64;

// monotone-increasing float->u32 mapping
__device__ __forceinline__ unsigned mono_u32(float f) {
    unsigned u = __float_as_uint(f);
    return (u & 0x80000000u) ? ~u : (u | 0x80000000u);
}

// monotonic grid barrier: barrier k complete when arrive >= GRID*k.
// Requires all GRID blocks co-resident (GRID = 1 block/CU here).
__device__ __forceinline__ void grid_barrier(unsigned* arrive, unsigned k) {
    __syncthreads();
    if (threadIdx.x == 0) {
        __threadfence();   // release prior global writes (device scope)
        __hip_atomic_fetch_add(arrive, 1u, __ATOMIC_ACQ_REL, __HIP_MEMORY_SCOPE_AGENT);
        unsigned target = (unsigned)GRID * k;
        while (__hip_atomic_load(arrive, __ATOMIC_ACQUIRE, __HIP_MEMORY_SCOPE_AGENT) < target) {
            __builtin_amdgcn_s_sleep(1);
        }
        __threadfence();   // acquire
    }
    __syncthreads();
}

__global__ __launch_bounds__(256) void fused_kernel(
    const float* __restrict__ score0, const float* __restrict__ bbox0, const float* __restrict__ kps0,
    const float* __restrict__ score1, const float* __restrict__ bbox1, const float* __restrict__ kps1,
    const float* __restrict__ score2, const float* __restrict__ bbox2, const float* __restrict__ kps2,
    float* __restrict__ logit, float* __restrict__ sig,
    float* __restrict__ box, float* __restrict__ kps,
    u64* __restrict__ key, int* __restrict__ rank, unsigned* __restrict__ cnt,
    u64* __restrict__ validw, u64* __restrict__ rowflag, u64* __restrict__ keep_words,
    int* __restrict__ nvalid, ulonglong2* __restrict__ ent, unsigned* __restrict__ arrive,
    float* __restrict__ s_logit, float* __restrict__ s_sig,
    float* __restrict__ s_box, float* __restrict__ s_kps,
    float* __restrict__ out)
{
    __shared__ u64 tileB[256];             // rank tile
    __shared__ float4 cbox[4][64];         // pairs: per-wave column boxes
    __shared__ float  carea[4][64];
    __shared__ unsigned short nlist[8448]; // nms: nonzero-row list (block 0)
    const int tid  = threadIdx.x;
    const int gtid = blockIdx.x * BTHR + tid;

    // ---------------- Phase A: decode + zero-init ----------------
    if (gtid < N_TOT) {
        int i = gtid;
        if (i == 0) *nvalid = 0;
        if (i < MASK_WORDS) { validw[i] = 0ull; rowflag[i] = 0ull; }
        rank[i] = 0;
        cnt[i] = 0u;
        const float *sc, *bb, *kp;
        int m, F; float s;
        if (i < 6400)      { sc = score0; bb = bbox0; kp = kps0; m = i;        F = 80; s = 8.f;  }
        else if (i < 8000) { sc = score1; bb = bbox1; kp = kps1; m = i - 6400; F = 40; s = 16.f; }
        else               { sc = score2; bb = bbox2; kp = kps2; m = i - 8000; F = 20; s = 32.f; }
        float px = (float)(m % F) * s;
        float py = (float)(m / F) * s;
        float lg = sc[m];
        logit[i] = lg;
        sig[i] = 1.0f / (1.0f + expf(-lg));
        key[i] = ((u64)(~mono_u32(lg)) << 14) | (u64)i;
        float d0 = bb[m*4+0]*s, d1 = bb[m*4+1]*s, d2 = bb[m*4+2]*s, d3 = bb[m*4+3]*s;
        box[i*4+0] = px - d0;
        box[i*4+1] = py - d1;
        box[i*4+2] = px + d2;
        box[i*4+3] = py + d3;
        #pragma unroll
        for (int c = 0; c < 5; ++c) {
            kps[i*10 + 2*c]   = px + kp[m*10 + 2*c]   * s;
            kps[i*10 + 2*c+1] = py + kp[m*10 + 2*c+1] * s;
        }
    }
    grid_barrier(arrive, 1);

    // ---------------- Phase B: tiled rank = #{j : key[j] < key[i]} ----------------
    for (int t = blockIdx.x; t < RT * RT; t += GRID) {
        int bi = t / RT, bj = t % RT;
        int j = bj * 256 + tid;
        tileB[tid] = (j < N_TOT) ? key[j] : ~0ull;
        __syncthreads();
        int i = bi * 256 + tid;
        if (i < N_TOT) {
            u64 ki = key[i];
            int rk = 0;
            #pragma unroll 8
            for (int k = 0; k < 256; ++k) rk += (tileB[k] < ki) ? 1 : 0;
            if (rk) atomicAdd(&rank[i], rk);
        }
        __syncthreads();
    }
    grid_barrier(arrive, 2);

    // ---------------- Phase C: scatter into sorted order + count V ----------------
    {
        float lg = -1.f;
        if (gtid < N_TOT) {
            int i = gtid;
            int r = rank[i];
            lg = logit[i];
            s_logit[r] = lg;
            s_sig[r] = sig[i];
            #pragma unroll
            for (int c = 0; c < 4; ++c)  s_box[r*4+c] = box[i*4+c];
            #pragma unroll
            for (int c = 0; c < 10; ++c) s_kps[r*10+c] = kps[i*10+c];
            if (lg > 0.f) atomicOr(&validw[r >> 6], 1ull << (r & 63));
        }
        u64 vb = __ballot(lg > 0.f);
        if ((tid & 63) == 0 && vb) atomicAdd(nvalid, (int)__popcll(vb));
    }
    grid_barrier(arrive, 3);

    // ---------------- Phase D: successor pairs over valid-prefix triangle ----------------
    {
        int wv = tid >> 6;
        int lane = tid & 63;
        int wgid = blockIdx.x * 4 + wv;
        const int V = *nvalid;            // valid ranks are prefix [0,V)
        const int nw = (V + 63) >> 6;
        const int T = nw * (nw + 1) / 2;  // tiles rb<=cw<nw
        const float4* sbox4 = (const float4*)s_box;

        for (int t = wgid; t < T; t += GRID * 4) {
            float fn = (float)nw + 0.5f;
            int rb = (int)(fn - sqrtf(fn * fn - 2.0f * (float)t));
            if (rb < 0) rb = 0;
            while (rb > 0 && (rb * nw - (rb * (rb - 1)) / 2) > t) --rb;
            while (((rb + 1) * nw - ((rb + 1) * rb) / 2) <= t) ++rb;
            int cw = rb + (t - (rb * nw - (rb * (rb - 1)) / 2));

            int j = cw * 64 + lane;
            float4 cb = (j < N_TOT) ? sbox4[j] : make_float4(0.f, 0.f, 0.f, 0.f);
            cbox[wv][lane] = cb;
            carea[wv][lane] = (cb.z - cb.x) * (cb.w - cb.y);
            __builtin_amdgcn_s_waitcnt(0);   // LDS writes visible within wave

            int r = rb * 64 + lane;
            float4 r4 = (r < N_TOT) ? sbox4[r] : make_float4(0.f, 0.f, 0.f, 0.f);
            float rarea = (r4.z - r4.x) * (r4.w - r4.y);
            u64 bits = 0ull;
            #pragma unroll 4
            for (int k = 0; k < 64; ++k) {
                float4 c4 = cbox[wv][k];
                float cak = carea[wv][k];
                float ltx = fmaxf(r4.x, c4.x);
                float lty = fmaxf(r4.y, c4.y);
                float rbx = fminf(r4.z, c4.z);
                float rby = fminf(r4.w, c4.w);
                float w = fmaxf(rbx - ltx, 0.f);
                float h = fmaxf(rby - lty, 0.f);
                float inter = w * h;
                float iou = inter / (rarea + cak - inter + 1e-9f);
                bits |= (iou > 0.4f) ? (1ull << k) : 0ull;
            }
            // prefix validity: column j valid iff j < V
            int nvc = V - cw * 64;
            u64 cvalid = (nvc >= 64) ? ~0ull : ((nvc <= 0) ? 0ull : ((1ull << nvc) - 1ull));
            u64 m = cvalid;
            if (cw == rb) m &= (lane == 63) ? 0ull : (~0ull << (lane + 1));  // strict successors
            bits &= (r < V) ? m : 0ull;

            if (bits) {
                unsigned idx = atomicAdd(&cnt[r], 1u);
                if (idx < CAP) {
                    ulonglong2 e; e.x = bits; e.y = (u64)cw;
                    ent[(size_t)r * CAP + idx] = e;
                }
                atomicOr(&rowflag[r >> 6], 1ull << (r & 63));
            }
        }
    }
    grid_barrier(arrive, 4);

    // ---------------- Phase E: serial greedy resolve (block 0, wave 0) ----------------
    if (blockIdx.x == 0 && tid < 64) {
        int lane = tid;
        u64 rf[3], vw[3];
        #pragma unroll
        for (int s = 0; s < 3; ++s) {
            int w = s * 64 + lane;
            rf[s] = (w < MASK_WORDS) ? rowflag[w] : 0ull;
            vw[s] = (w < MASK_WORDS) ? validw[w] : 0ull;
        }
        // sorted nonzero-row list via wave prefix sums
        int base = 0;
        #pragma unroll
        for (int s = 0; s < 3; ++s) {
            int c = (int)__popcll(rf[s]);
            int x = c;
            #pragma unroll
            for (int o = 1; o < 64; o <<= 1) { int y = __shfl_up(x, o); if (lane >= o) x += y; }
            int excl = x - c;
            int total = __shfl(x, 63);
            int off = base + excl;
            u64 t = rf[s];
            int wbase = (s * 64 + lane) << 6;
            while (t) {
                int b = __builtin_ctzll(t); t &= t - 1;
                nlist[off++] = (unsigned short)(wbase | b);
            }
            base += total;
        }
        int n_nz = base;

        u64 rem0 = 0ull, rem1 = 0ull, rem2 = 0ull;
        if (n_nz > 0) {
            int half = lane >> 5;
            int sub  = lane & 31;
            int idx0 = min(sub, n_nz - 1);
            int rowCur = nlist[idx0];
            unsigned cntCur = cnt[rowCur];
            ulonglong2 entCur = ent[(size_t)rowCur * CAP + half];

            for (int k0 = 0; k0 < n_nz; k0 += 32) {
                int nb = k0 + 32;
                int rowNxt = 0; unsigned cntNxt = 0u;
                ulonglong2 entNxt; entNxt.x = 0ull; entNxt.y = 0ull;
                if (nb < n_nz) {
                    int idx = min(nb + sub, n_nz - 1);
                    rowNxt = nlist[idx];
                    cntNxt = cnt[rowNxt];
                    entNxt = ent[(size_t)rowNxt * CAP + half];
                }
                int lim = min(32, n_nz - k0);
                for (int i = 0; i < lim; ++i) {
                    int r = __builtin_amdgcn_readlane(rowCur, i);
                    int w = r >> 6, slot = w >> 6, owner = w & 63, b = r & 63;
                    u64 rw = (slot == 0) ? rem0 : ((slot == 1) ? rem1 : rem2);
                    unsigned halfw = (b < 32) ? (unsigned)rw : (unsigned)(rw >> 32);
                    unsigned word = (unsigned)__builtin_amdgcn_readlane((int)halfw, owner);
                    if (!((word >> (b & 31)) & 1u)) {
                        unsigned c = (unsigned)__builtin_amdgcn_readlane((int)cntCur, i);
                        int ec = (int)min(c, 2u);
                        for (int e = 0; e < ec; ++e) {
                            int src = e * 32 + i;
                            unsigned ey  = (unsigned)__builtin_amdgcn_readlane((int)(unsigned)entCur.y, src);
                            unsigned blo = (unsigned)__builtin_amdgcn_readlane((int)(unsigned)entCur.x, src);
                            unsigned bhi = (unsigned)__builtin_amdgcn_readlane((int)(unsigned)(entCur.x >> 32), src);
                            u64 bits = ((u64)bhi << 32) | (u64)blo;
                            int es = (int)(ey >> 6), eo = (int)(ey & 63u);
                            u64 add = (lane == eo) ? bits : 0ull;
                            if (es == 0) rem0 |= add; else if (es == 1) rem1 |= add; else rem2 |= add;
                        }
                        if (c > 2u) {
                            unsigned cm = min(c, (unsigned)CAP);
                            for (unsigned e = 2; e < cm; ++e) {
                                ulonglong2 g = ent[(size_t)r * CAP + e];
                                int es = (int)(g.y >> 6), eo = (int)(g.y & 63u);
                                u64 add = (lane == eo) ? g.x : 0ull;
                                if (es == 0) rem0 |= add; else if (es == 1) rem1 |= add; else rem2 |= add;
                            }
                        }
                    }
                }
                rowCur = rowNxt; cntCur = cntNxt; entCur = entNxt;
            }
        }
        #pragma unroll
        for (int s = 0; s < 3; ++s) {
            int w = s * 64 + lane;
            u64 rems = (s == 0) ? rem0 : ((s == 1) ? rem1 : rem2);
            if (w < MASK_WORDS) keep_words[w] = vw[s] & ~rems;
        }
    }
    grid_barrier(arrive, 5);

    // ---------------- Phase F: write outputs ----------------
    if (gtid < N_TOT) {
        int r = gtid;
        float m = ((keep_words[r >> 6] >> (r & 63)) & 1ull) ? 1.0f : 0.0f;
        float* ob = out;                   // 8400*4
        float* os = out + 33600;           // 8400
        float* okp = out + 42000;          // 8400*10
        float* om = out + 126000;          // 8400
        float4 b4 = ((const float4*)s_box)[r];
        b4.x *= m; b4.y *= m; b4.z *= m; b4.w *= m;
        ((float4*)ob)[r] = b4;
        os[r] = s_sig[r] * m;
        #pragma unroll
        for (int c = 0; c < 10; ++c) okp[r*10+c] = s_kps[r*10+c] * m;
        om[r] = m;
    }
}

extern "C" void kernel_launch(void* const* d_in, const int* in_sizes, int n_in,
                              void* d_out, int out_size, void* d_ws, size_t ws_size,
                              hipStream_t stream) {
    const float *score0, *bbox0, *kps0, *score1, *bbox1, *kps1, *score2, *bbox2, *kps2;
    if (in_sizes[1] == 25600) {
        score0 = (const float*)d_in[0]; bbox0 = (const float*)d_in[1]; kps0 = (const float*)d_in[2];
        score1 = (const float*)d_in[3]; bbox1 = (const float*)d_in[4]; kps1 = (const float*)d_in[5];
        score2 = (const float*)d_in[6]; bbox2 = (const float*)d_in[7]; kps2 = (const float*)d_in[8];
    } else {
        score0 = (const float*)d_in[0]; score1 = (const float*)d_in[1]; score2 = (const float*)d_in[2];
        bbox0  = (const float*)d_in[3]; bbox1  = (const float*)d_in[4]; bbox2  = (const float*)d_in[5];
        kps0   = (const float*)d_in[6]; kps1   = (const float*)d_in[7]; kps2   = (const float*)d_in[8];
    }

    char* ws = (char*)d_ws;
    float* logit   = (float*)(ws + 0);
    float* sig     = (float*)(ws + 33600);
    float* box     = (float*)(ws + 67200);
    float* kps     = (float*)(ws + 201600);
    int*   rank    = (int*)  (ws + 537600);
    float* s_logit = (float*)(ws + 571200);
    float* s_sig   = (float*)(ws + 604800);
    float* s_box   = (float*)(ws + 638400);          // 16B-aligned (float4 loads)
    float* s_kps   = (float*)(ws + 772800);          // ends 1108800
    u64*   keep_words = (u64*)(ws + 1108800);        // 1056 B
    u64*   validw     = (u64*)(ws + 1110144);        // 1056 B
    u64*   rowflag    = (u64*)(ws + 1111296);        // 1056 B
    int*   nvalid     = (int*)(ws + 1112384);        // 4 B
    unsigned* arrive  = (unsigned*)(ws + 1112388);   // 4 B (barrier counter)
    unsigned int* cnt = (unsigned int*)(ws + 1112448);   // 33600 B
    u64*   key        = (u64*)(ws + 1146368);            // 67200 B
    ulonglong2*   ent = (ulonglong2*)(ws + 1213568);     // 8400*32*16 = 4.3 MB

    float* out = (float*)d_out;

    hipMemsetAsync(arrive, 0, sizeof(unsigned), stream);   // zero barrier counter (ws is poisoned)
    fused_kernel<<<GRID, BTHR, 0, stream>>>(
        score0, bbox0, kps0, score1, bbox1, kps1, score2, bbox2, kps2,
        logit, sig, box, kps, key, rank, cnt,
        validw, rowflag, keep_words, nvalid, ent, arrive,
        s_logit, s_sig, s_box, s_kps, out);
}

// Round 9
// 157.010 us; speedup vs baseline: 1.5012x; 1.5012x over previous
//
#include <hip/hip_runtime.h>
#include <math.h>

#define N_TOT 8400
#define MASK_WORDS 132   // ceil(8400/64)
#define CAP 32           // max (word,bits) entries per row
#define KTHR 1024        // ranksort block threads
#define KBLK 132         // ranksort blocks (64 rows each)
#define JSPLIT 16        // j-ranges per block (8400/16 = 525)
#define JLEN 525
#define PBLK 1024        // pairs blocks
#define VALID_THRESH (0x7fffffffull << 14)   // key < this  <=>  logit > 0

typedef unsigned long long u64;

// monotone-increasing float->u32 mapping
__device__ __forceinline__ unsigned mono_u32(float f) {
    unsigned u = __float_as_uint(f);
    return (u & 0x80000000u) ? ~u : (u | 0x80000000u);
}

// ---------------- K1: keys in LDS -> exact rank -> direct decode+scatter ----------------
// Block b owns original rows [64b, 64b+64). All 8400 keys are built in LDS from raw
// scores; thread (q,i) counts keys[j] < key[row_i] over j-range q (LDS broadcast reads,
// conflict-free). Wave 0 then sums partials, decodes its rows from the raw inputs and
// scatters straight into the sorted arrays. Also: block 0 counts V (valid = key below
// VALID_THRESH) and zeros ticket; every block zeros its cnt slice + rowflag word.
__global__ __launch_bounds__(1024) void ranksort_kernel(
    const float* __restrict__ score0, const float* __restrict__ bbox0, const float* __restrict__ kps0,
    const float* __restrict__ score1, const float* __restrict__ bbox1, const float* __restrict__ kps1,
    const float* __restrict__ score2, const float* __restrict__ bbox2, const float* __restrict__ kps2,
    float* __restrict__ s_sig, float* __restrict__ s_box, float* __restrict__ s_kps,
    unsigned* __restrict__ cnt, u64* __restrict__ rowflag,
    int* __restrict__ nvalid, unsigned* __restrict__ ticket)
{
    __shared__ u64 keys[N_TOT];
    __shared__ int part[JSPLIT][64];
    __shared__ int vcnt;
    const int tid = threadIdx.x;
    const int bid = blockIdx.x;

    if (tid == 0) vcnt = 0;
    for (int idx = tid; idx < N_TOT; idx += KTHR) {
        const float* sc; int m;
        if (idx < 6400)      { sc = score0; m = idx; }
        else if (idx < 8000) { sc = score1; m = idx - 6400; }
        else                 { sc = score2; m = idx - 8000; }
        float lg = sc[m];
        // descending logit, ascending index tie-break, as one ascending u64 key
        keys[idx] = ((u64)(~mono_u32(lg)) << 14) | (u64)idx;
    }
    __syncthreads();

    // block 0: count valid (logit>0) from key bits
    if (bid == 0) {
        int c = 0;
        for (int idx = tid; idx < N_TOT; idx += KTHR)
            c += (keys[idx] < VALID_THRESH) ? 1 : 0;
        #pragma unroll
        for (int o = 32; o >= 1; o >>= 1) c += __shfl_down(c, o);
        if ((tid & 63) == 0 && c) atomicAdd(&vcnt, c);
    }

    // rank partials: thread (q,i) scans j-range q for row i
    const int i = tid & 63;
    const int q = tid >> 6;
    const int row = bid * 64 + i;
    u64 ki = keys[(row < N_TOT) ? row : (N_TOT - 1)];
    int c = 0;
    const int j0 = q * JLEN;
    #pragma unroll 5
    for (int j = j0; j < j0 + JLEN; ++j)
        c += (keys[j] < ki) ? 1 : 0;
    part[q][i] = c;
    __syncthreads();

    if (bid == 0 && tid == 0) { *nvalid = vcnt; *ticket = 0u; }
    if (tid == 64) rowflag[bid] = 0ull;            // bid in [0,132)=MASK_WORDS
    if (tid < 64 && row < N_TOT) {
        int rk = 0;
        #pragma unroll
        for (int qq = 0; qq < JSPLIT; ++qq) rk += part[qq][tid];
        cnt[row] = 0u;                             // rows enumerate [0,8400) across blocks
        // decode this original row directly from inputs
        const float *sc, *bb, *kp; int m, F; float s;
        if (row < 6400)      { sc=score0; bb=bbox0; kp=kps0; m=row;      F=80; s=8.f;  }
        else if (row < 8000) { sc=score1; bb=bbox1; kp=kps1; m=row-6400; F=40; s=16.f; }
        else                 { sc=score2; bb=bbox2; kp=kps2; m=row-8000; F=20; s=32.f; }
        float px = (float)(m % F) * s;
        float py = (float)(m / F) * s;
        float lg = sc[m];
        s_sig[rk] = 1.0f / (1.0f + expf(-lg));
        float4 b4;
        b4.x = px - bb[m*4+0]*s;
        b4.y = py - bb[m*4+1]*s;
        b4.z = px + bb[m*4+2]*s;
        b4.w = py + bb[m*4+3]*s;
        ((float4*)s_box)[rk] = b4;
        #pragma unroll
        for (int k = 0; k < 5; ++k) {
            s_kps[rk*10 + 2*k]   = px + kp[m*10 + 2*k]   * s;
            s_kps[rk*10 + 2*k+1] = py + kp[m*10 + 2*k+1] * s;
        }
    }
}

// ---------------- K2: successor pairs over valid triangle + last-block serial NMS ----------------
__global__ __launch_bounds__(256) void pairs_nms_kernel(
    const float* __restrict__ s_box,
    const int* __restrict__ nvalid,
    unsigned* __restrict__ cnt,
    ulonglong2* __restrict__ ent,
    u64* __restrict__ rowflag,
    unsigned* __restrict__ ticket,
    u64* __restrict__ keep_words)
{
    __shared__ unsigned short nlist[8448];
    __shared__ bool isLast;
    const int tid = threadIdx.x;
    const int wv = tid >> 6;
    const int lane = tid & 63;
    const int V = *nvalid;                 // valid ranks are prefix [0,V)
    const int nw = (V + 63) >> 6;
    const int T = nw * (nw + 1) / 2;       // triangle tiles rb<=cw<nw
    const float4* sbox4 = (const float4*)s_box;

    for (int t = blockIdx.x * 4 + wv; t < T; t += gridDim.x * 4) {
        // t -> (rb, cw): S(rb) = rb*nw - rb(rb-1)/2
        float fn = (float)nw + 0.5f;
        int rb = (int)(fn - sqrtf(fn * fn - 2.0f * (float)t));
        if (rb < 0) rb = 0;
        while (rb > 0 && (rb * nw - (rb * (rb - 1)) / 2) > t) --rb;
        while (((rb + 1) * nw - ((rb + 1) * rb) / 2) <= t) ++rb;
        int cw = rb + (t - (rb * nw - (rb * (rb - 1)) / 2));

        int j = cw * 64 + lane;
        float4 cb = (j < N_TOT) ? sbox4[j] : make_float4(0.f, 0.f, 0.f, 0.f);
        int r = rb * 64 + lane;
        float4 r4 = (r < N_TOT) ? sbox4[r] : make_float4(0.f, 0.f, 0.f, 0.f);
        float rarea = (r4.z - r4.x) * (r4.w - r4.y);
        float ca = (cb.z - cb.x) * (cb.w - cb.y);
        u64 bits = 0ull;
        #pragma unroll 4
        for (int k = 0; k < 64; ++k) {     // all lanes active -> shfl well-defined
            float cx1 = __shfl(cb.x, k);
            float cy1 = __shfl(cb.y, k);
            float cx2 = __shfl(cb.z, k);
            float cy2 = __shfl(cb.w, k);
            float cak = __shfl(ca, k);
            float ltx = fmaxf(r4.x, cx1);
            float lty = fmaxf(r4.y, cy1);
            float rbx = fminf(r4.z, cx2);
            float rby = fminf(r4.w, cy2);
            float w = fmaxf(rbx - ltx, 0.f);
            float h = fmaxf(rby - lty, 0.f);
            float inter = w * h;
            float iou = inter / (rarea + cak - inter + 1e-9f);
            bits |= (iou > 0.4f) ? (1ull << k) : 0ull;
        }
        // prefix validity for columns
        int nvc = V - cw * 64;
        u64 cvalid = (nvc >= 64) ? ~0ull : ((nvc <= 0) ? 0ull : ((1ull << nvc) - 1ull));
        u64 m = cvalid;
        if (cw == rb) m &= (lane == 63) ? 0ull : (~0ull << (lane + 1));  // strict successors
        bits &= (r < V) ? m : 0ull;

        if (bits) {
            unsigned idx = atomicAdd(&cnt[r], 1u);
            if (idx < CAP) {
                ulonglong2 e; e.x = bits; e.y = (u64)cw;
                ent[(size_t)r * CAP + idx] = e;
            }
            atomicOr(&rowflag[r >> 6], 1ull << (r & 63));
        }
    }

    // release this block's writes, then ticket; last block resolves
    __threadfence();
    __syncthreads();
    if (tid == 0) {
        unsigned tk = atomicAdd(ticket, 1u);
        isLast = (tk == gridDim.x - 1);
    }
    __syncthreads();
    if (!isLast) return;
    __threadfence();   // acquire: see all blocks' ent/cnt/rowflag

    if (tid < 64) {
        u64 rf[3], vw[3];
        #pragma unroll
        for (int s = 0; s < 3; ++s) {
            int w = s * 64 + lane;
            rf[s] = (w < MASK_WORDS) ? rowflag[w] : 0ull;
            int nb = V - w * 64;
            vw[s] = (w >= MASK_WORDS || nb <= 0) ? 0ull
                  : ((nb >= 64) ? ~0ull : ((1ull << nb) - 1ull));
        }
        // sorted nonzero-row list via wave prefix sums
        int base = 0;
        #pragma unroll
        for (int s = 0; s < 3; ++s) {
            int c = (int)__popcll(rf[s]);
            int x = c;
            #pragma unroll
            for (int o = 1; o < 64; o <<= 1) { int y = __shfl_up(x, o); if (lane >= o) x += y; }
            int excl = x - c;
            int total = __shfl(x, 63);
            int off = base + excl;
            u64 t = rf[s];
            int wbase = (s * 64 + lane) << 6;
            while (t) {
                int b = __builtin_ctzll(t); t &= t - 1;
                nlist[off++] = (unsigned short)(wbase | b);
            }
            base += total;
        }
        int n_nz = base;

        u64 rem0 = 0ull, rem1 = 0ull, rem2 = 0ull;
        if (n_nz > 0) {
            int half = lane >> 5;
            int sub  = lane & 31;
            int idx0 = min(sub, n_nz - 1);
            int rowCur = nlist[idx0];
            unsigned cntCur = cnt[rowCur];
            ulonglong2 entCur = ent[(size_t)rowCur * CAP + half];

            for (int k0 = 0; k0 < n_nz; k0 += 32) {
                int nb2 = k0 + 32;
                int rowNxt = 0; unsigned cntNxt = 0u;
                ulonglong2 entNxt; entNxt.x = 0ull; entNxt.y = 0ull;
                if (nb2 < n_nz) {
                    int idx = min(nb2 + sub, n_nz - 1);
                    rowNxt = nlist[idx];
                    cntNxt = cnt[rowNxt];
                    entNxt = ent[(size_t)rowNxt * CAP + half];
                }
                int lim = min(32, n_nz - k0);
                for (int i = 0; i < lim; ++i) {
                    int r = __builtin_amdgcn_readlane(rowCur, i);
                    int w = r >> 6, slot = w >> 6, owner = w & 63, b = r & 63;
                    u64 rw = (slot == 0) ? rem0 : ((slot == 1) ? rem1 : rem2);
                    unsigned halfw = (b < 32) ? (unsigned)rw : (unsigned)(rw >> 32);
                    unsigned word = (unsigned)__builtin_amdgcn_readlane((int)halfw, owner);
                    if (!((word >> (b & 31)) & 1u)) {
                        unsigned c = (unsigned)__builtin_amdgcn_readlane((int)cntCur, i);
                        int ec = (int)min(c, 2u);
                        for (int e = 0; e < ec; ++e) {
                            int src = e * 32 + i;
                            unsigned ey  = (unsigned)__builtin_amdgcn_readlane((int)(unsigned)entCur.y, src);
                            unsigned blo = (unsigned)__builtin_amdgcn_readlane((int)(unsigned)entCur.x, src);
                            unsigned bhi = (unsigned)__builtin_amdgcn_readlane((int)(unsigned)(entCur.x >> 32), src);
                            u64 bits = ((u64)bhi << 32) | (u64)blo;
                            int es = (int)(ey >> 6), eo = (int)(ey & 63u);
                            u64 add = (lane == eo) ? bits : 0ull;
                            if (es == 0) rem0 |= add; else if (es == 1) rem1 |= add; else rem2 |= add;
                        }
                        if (c > 2u) {
                            unsigned cm = min(c, (unsigned)CAP);
                            for (unsigned e = 2; e < cm; ++e) {
                                ulonglong2 g = ent[(size_t)r * CAP + e];
                                int es = (int)(g.y >> 6), eo = (int)(g.y & 63u);
                                u64 add = (lane == eo) ? g.x : 0ull;
                                if (es == 0) rem0 |= add; else if (es == 1) rem1 |= add; else rem2 |= add;
                            }
                        }
                    }
                }
                rowCur = rowNxt; cntCur = cntNxt; entCur = entNxt;
            }
        }
        #pragma unroll
        for (int s = 0; s < 3; ++s) {
            int w = s * 64 + lane;
            u64 rems = (s == 0) ? rem0 : ((s == 1) ? rem1 : rem2);
            if (w < MASK_WORDS) keep_words[w] = vw[s] & ~rems;
        }
    }
}

// ---------------- K3: write outputs ----------------
__global__ __launch_bounds__(256) void output_kernel(const float* __restrict__ s_sig,
                              const float* __restrict__ s_box,
                              const float* __restrict__ s_kps,
                              const u64* __restrict__ keep_words,
                              float* __restrict__ out) {
    int r = blockIdx.x * blockDim.x + threadIdx.x;
    if (r >= N_TOT) return;
    float m = ((keep_words[r >> 6] >> (r & 63)) & 1ull) ? 1.0f : 0.0f;
    float* ob = out;                   // 8400*4
    float* os = out + 33600;           // 8400
    float* okp = out + 42000;          // 8400*10
    float* om = out + 126000;          // 8400
    float4 b4 = ((const float4*)s_box)[r];
    b4.x *= m; b4.y *= m; b4.z *= m; b4.w *= m;
    ((float4*)ob)[r] = b4;
    os[r] = s_sig[r] * m;
    #pragma unroll
    for (int c = 0; c < 10; ++c) okp[r*10+c] = s_kps[r*10+c] * m;
    om[r] = m;
}

extern "C" void kernel_launch(void* const* d_in, const int* in_sizes, int n_in,
                              void* d_out, int out_size, void* d_ws, size_t ws_size,
                              hipStream_t stream) {
    const float *score0, *bbox0, *kps0, *score1, *bbox1, *kps1, *score2, *bbox2, *kps2;
    if (in_sizes[1] == 25600) {
        score0 = (const float*)d_in[0]; bbox0 = (const float*)d_in[1]; kps0 = (const float*)d_in[2];
        score1 = (const float*)d_in[3]; bbox1 = (const float*)d_in[4]; kps1 = (const float*)d_in[5];
        score2 = (const float*)d_in[6]; bbox2 = (const float*)d_in[7]; kps2 = (const float*)d_in[8];
    } else {
        score0 = (const float*)d_in[0]; score1 = (const float*)d_in[1]; score2 = (const float*)d_in[2];
        bbox0  = (const float*)d_in[3]; bbox1  = (const float*)d_in[4]; bbox2  = (const float*)d_in[5];
        kps0   = (const float*)d_in[6]; kps1   = (const float*)d_in[7]; kps2   = (const float*)d_in[8];
    }

    char* ws = (char*)d_ws;
    float* s_box   = (float*)(ws + 0);               // 134400 B (16B aligned)
    float* s_kps   = (float*)(ws + 134400);          // 336000 B
    float* s_sig   = (float*)(ws + 470400);          // 33600 B
    u64*   keep_words = (u64*)(ws + 504000);         // 1056 B
    u64*   rowflag    = (u64*)(ws + 505088);         // 1056 B
    unsigned int* cnt = (unsigned int*)(ws + 506144);// 33600 B
    int*   nvalid     = (int*)(ws + 539744);         // 4 B
    unsigned* ticket  = (unsigned*)(ws + 539748);    // 4 B
    ulonglong2* ent   = (ulonglong2*)(ws + 539760);  // 8400*32*16 = 4.3 MB

    float* out = (float*)d_out;

    ranksort_kernel<<<KBLK, KTHR, 0, stream>>>(
        score0, bbox0, kps0, score1, bbox1, kps1, score2, bbox2, kps2,
        s_sig, s_box, s_kps, cnt, rowflag, nvalid, ticket);
    pairs_nms_kernel<<<PBLK, 256, 0, stream>>>(
        s_box, nvalid, cnt, ent, rowflag, ticket, keep_words);
    output_kernel<<<33, 256, 0, stream>>>(s_sig, s_box, s_kps, keep_words, out);
}